// Round 4
// baseline (340.016 us; speedup 1.0000x reference)
//
#include <hip/hip_runtime.h>
#include <hip/hip_bf16.h>

constexpr int BB = 2;        // batch
constexpr int CC = 128;      // channels
constexpr int NN = 65536;    // H*W pixels
constexpr int MM = 1024;     // N / chunks
constexpr int LASTOFF = 63 * 1024;   // pixel offset of last chunk
constexpr float INV_T = 1.0f / 0.07f;
constexpr float L2E = 1.44269504088896340736f;  // log2(e)
constexpr float C2 = INV_T * L2E;               // fold /T and ln->log2 into A side
// loss = accum_base2 / (count * L2E); count = B*chunks*M*(M+1) = 134348800
constexpr float SCALE = 1.0f / (134348800.0f * 1.44269504088896340736f);
constexpr float EPSN = 1e-12f;

typedef float f32x4 __attribute__((ext_vector_type(4)));
typedef short bf16x8 __attribute__((ext_vector_type(8)));

__device__ __forceinline__ uint pack_bf16(float a, float b) {
  __hip_bfloat16 ha = __float2bfloat16(a);
  __hip_bfloat16 hb = __float2bfloat16(b);
  ushort ua = *reinterpret_cast<ushort*>(&ha);
  ushort ub = *reinterpret_cast<ushort*>(&hb);
  return (uint)ua | ((uint)ub << 16);
}

// ---------------------------------------------------------------------------
// K1: streaming per-pixel norms + positive logit. No LDS, register-only.
// Block = 512 pixels (thread = 2 px via float2); full unroll -> ~32 loads in
// flight per lane for HBM latency hiding.
__global__ __launch_bounds__(256) void k_pos(
    const float* __restrict__ z1, const float* __restrict__ z2,
    float* __restrict__ i1c2, float* __restrict__ posv) {
  const int b = blockIdx.y;
  const int px = blockIdx.x * 512 + 2 * threadIdx.x;
  const float* p1 = z1 + (size_t)b * CC * NN + px;
  const float* p2 = z2 + (size_t)b * CC * NN + px;
  float s11a = 0.f, s22a = 0.f, s12a = 0.f;
  float s11b = 0.f, s22b = 0.f, s12b = 0.f;
#pragma unroll 16
  for (int c = 0; c < CC; c++) {
    float2 x = *reinterpret_cast<const float2*>(p1 + (size_t)c * NN);
    float2 y = *reinterpret_cast<const float2*>(p2 + (size_t)c * NN);
    s11a += x.x * x.x; s22a += y.x * y.x; s12a += x.x * y.x;
    s11b += x.y * x.y; s22b += y.y * y.y; s12b += x.y * y.y;
  }
  float i1a = 1.0f / fmaxf(sqrtf(s11a), EPSN);
  float i2a = 1.0f / fmaxf(sqrtf(s22a), EPSN);
  float i1b = 1.0f / fmaxf(sqrtf(s11b), EPSN);
  float i2b = 1.0f / fmaxf(sqrtf(s22b), EPSN);
  float2 iv = {i1a * C2, i1b * C2};
  float2 pv = {s12a * i1a * i2a * C2, s12b * i1b * i2b * C2};
  *reinterpret_cast<float2*>(i1c2 + (size_t)b * NN + px) = iv;
  *reinterpret_cast<float2*>(posv + (size_t)b * NN + px) = pv;
}

// ---------------------------------------------------------------------------
// K2: normalize + transpose + bf16 for z2's last chunk (B side, UNSCALED)
//     + per-label column-sum partials S_v = sum_{cl != v} col_n  (fp32 atomics).
__global__ __launch_bounds__(256) void k_r2(
    const float* __restrict__ z2, const int* __restrict__ lab,
    uint* __restrict__ r2n, float* __restrict__ Sv) {
  __shared__ float t2[64 * 129];
  __shared__ float part[8][65];
  __shared__ float inv2s[64];
  __shared__ int cls[64];
  const int b = blockIdx.y;
  const int pg = blockIdx.x * 64;          // within last chunk
  const int p0 = LASTOFF + pg;
  const int t = threadIdx.x;
  const int p2 = t & 31;
  const int q = t >> 5;
  const float* s2 = z2 + (size_t)b * CC * NN + p0 + 2 * p2;
  float a22 = 0.f, b22 = 0.f;
#pragma unroll
  for (int e = 0; e < 16; e++) {
    int c = e * 8 + q;
    float2 y = *reinterpret_cast<const float2*>(s2 + (size_t)c * NN);
    t2[(2 * p2) * 129 + c] = y.x;
    t2[(2 * p2 + 1) * 129 + c] = y.y;
    a22 += y.x * y.x;
    b22 += y.y * y.y;
  }
  part[q][2 * p2] = a22;
  part[q][2 * p2 + 1] = b22;
  __syncthreads();
  if (t < 64) {
    float s22 = 0.f;
#pragma unroll
    for (int qq = 0; qq < 8; qq++) s22 += part[qq][t];
    inv2s[t] = 1.0f / fmaxf(sqrtf(s22), EPSN);
    cls[t] = lab[(size_t)b * NN + p0 + t];
  }
  __syncthreads();
  const size_t obase = ((size_t)b * MM + pg) * 64;
#pragma unroll
  for (int e = 0; e < 16; e++) {
    int lin = e * 256 + t;
    int pp = lin >> 6;
    int cp = lin & 63;
    float i2 = inv2s[pp];
    float v0 = t2[pp * 129 + 2 * cp] * i2;
    float v1 = t2[pp * 129 + 2 * cp + 1] * i2;
    r2n[obase + (size_t)pp * 64 + cp] = pack_bf16(v0, v1);
  }
  // S_v partials: thread -> (channel c, pixel-half h)
  const int c = t & 127;
  const int h = t >> 7;
  float tot = 0.f, se0 = 0.f, se1 = 0.f, se2 = 0.f, se3 = 0.f, se4 = 0.f;
#pragma unroll
  for (int k = 0; k < 32; k++) {
    int pp = h * 32 + k;
    float val = t2[pp * 129 + c] * inv2s[pp];
    int lb = cls[pp];
    tot += val;
    se0 += (lb == 0) ? val : 0.f;
    se1 += (lb == 1) ? val : 0.f;
    se2 += (lb == 2) ? val : 0.f;
    se3 += (lb == 3) ? val : 0.f;
    se4 += (lb == 4) ? val : 0.f;
  }
  float* svb = Sv + b * 640 + c;
  atomicAdd(svb + 0 * 128, tot - se0);
  atomicAdd(svb + 1 * 128, tot - se1);
  atomicAdd(svb + 2 * 128, tot - se2);
  atomicAdd(svb + 3 * 128, tot - se3);
  atomicAdd(svb + 4 * 128, tot - se4);
}

// ---------------------------------------------------------------------------
// K3: pack S_v fp32 -> bf16 16-row extra B-tile (rows 5..15 zero).
__global__ void k_svpack(const float* __restrict__ Sv, ushort* __restrict__ r2x) {
  int i = blockIdx.x * 256 + threadIdx.x;  // 0..4095
  if (i >= BB * 16 * 128) return;
  int b = i >> 11, rr = (i >> 7) & 15, c = i & 127;
  float v = (rr < 5) ? Sv[b * 640 + rr * 128 + c] : 0.0f;
  __hip_bfloat16 h = __float2bfloat16(v);
  r2x[i] = *reinterpret_cast<ushort*>(&h);
}

// ---------------------------------------------------------------------------
// K4: fused {z1 normalize+transpose staging} + GEMM + mask + softmax-sum.
// 128 px/block, 4 waves x 32 rows x all 1024 cols. Small register footprint
// (av 32 + transient bv 16 + acc 8 live) -> target 4 waves/SIMD for latency
// hiding; LDS 33 KB -> 4 blocks/CU. B chunk (16 KB) stays L1-hot.
// C/D layout: col = lane&15, row = (lane>>4)*4 + reg.
__global__ __launch_bounds__(256, 4) void k_gemm(
    const float* __restrict__ z1, const float* __restrict__ i1c2,
    const ushort* __restrict__ r2n, const ushort* __restrict__ r2x,
    const int* __restrict__ lab, const float* __restrict__ posv,
    float* __restrict__ accum) {
  __shared__ ushort At[128 * 130];   // [c][px], px<128, +2 pad = 33,280 B
  const int b = blockIdx.y;
  const int px0 = blockIdx.x * 128;
  const int tid = threadIdx.x;
  const int w = tid >> 6;
  const int lane = tid & 63;
  const int r = lane & 15;
  const int kg = lane >> 4;

  // --- stage A: normalize+scale+transpose z1 tile into LDS ---
  {
    const int pxl = 2 * (tid & 63);
    const int cg = tid >> 6;  // 0..3
    const float* zb = z1 + (size_t)b * CC * NN + px0 + pxl;
    float2 iv = *reinterpret_cast<const float2*>(i1c2 + (size_t)b * NN + px0 + pxl);
#pragma unroll
    for (int e = 0; e < 32; e++) {
      int c = e * 4 + cg;
      float2 v = *reinterpret_cast<const float2*>(zb + (size_t)c * NN);
      *reinterpret_cast<uint*>(&At[c * 130 + pxl]) = pack_bf16(v.x * iv.x, v.y * iv.y);
    }
  }
  __syncthreads();

  const int wrow0 = w * 32;
  // A fragments (one-time LDS gather)
  bf16x8 av[2][4];
#pragma unroll
  for (int g = 0; g < 2; g++)
#pragma unroll
    for (int kk = 0; kk < 4; kk++) {
      bf16x8 tv;
#pragma unroll
      for (int j = 0; j < 8; j++)
        tv[j] = (short)At[(kg * 8 + kk * 32 + j) * 130 + wrow0 + g * 16 + r];
      av[g][kk] = tv;
    }

  int rl[8];
#pragma unroll
  for (int g = 0; g < 2; g++)
#pragma unroll
    for (int i = 0; i < 4; i++)
      rl[g * 4 + i] = lab[(size_t)b * NN + px0 + wrow0 + g * 16 + kg * 4 + i];

  float sAcc[8];
#pragma unroll
  for (int s = 0; s < 8; s++) sAcc[s] = 0.f;

  const ushort* Bbase = r2n + (size_t)b * MM * CC;
  const int* clbase = lab + (size_t)b * NN + LASTOFF;

#pragma unroll
  for (int ch = 0; ch < 16; ch++) {
    const int n0 = ch * 64;
#pragma unroll
    for (int tt = 0; tt < 4; tt++) {
      const ushort* Bt = Bbase + (size_t)(n0 + tt * 16 + r) * CC + kg * 8;
      bf16x8 bv0 = *reinterpret_cast<const bf16x8*>(Bt);
      bf16x8 bv1 = *reinterpret_cast<const bf16x8*>(Bt + 32);
      bf16x8 bv2 = *reinterpret_cast<const bf16x8*>(Bt + 64);
      bf16x8 bv3 = *reinterpret_cast<const bf16x8*>(Bt + 96);
      int cl = clbase[n0 + tt * 16 + r];
      f32x4 a0 = {0.f, 0.f, 0.f, 0.f};
      f32x4 a1 = {0.f, 0.f, 0.f, 0.f};
      a0 = __builtin_amdgcn_mfma_f32_16x16x32_bf16(av[0][0], bv0, a0, 0, 0, 0);
      a1 = __builtin_amdgcn_mfma_f32_16x16x32_bf16(av[1][0], bv0, a1, 0, 0, 0);
      a0 = __builtin_amdgcn_mfma_f32_16x16x32_bf16(av[0][1], bv1, a0, 0, 0, 0);
      a1 = __builtin_amdgcn_mfma_f32_16x16x32_bf16(av[1][1], bv1, a1, 0, 0, 0);
      a0 = __builtin_amdgcn_mfma_f32_16x16x32_bf16(av[0][2], bv2, a0, 0, 0, 0);
      a1 = __builtin_amdgcn_mfma_f32_16x16x32_bf16(av[1][2], bv2, a1, 0, 0, 0);
      a0 = __builtin_amdgcn_mfma_f32_16x16x32_bf16(av[0][3], bv3, a0, 0, 0, 0);
      a1 = __builtin_amdgcn_mfma_f32_16x16x32_bf16(av[1][3], bv3, a1, 0, 0, 0);
      // masked exp2 accumulation (acc already = logit*C2; masked -> exp2(0)=1)
#pragma unroll
      for (int i = 0; i < 4; i++) {
        float x0 = (rl[i] != cl) ? a0[i] : 0.0f;
        float x1 = (rl[4 + i] != cl) ? a1[i] : 0.0f;
        sAcc[i] += __builtin_amdgcn_exp2f(x0);
        sAcc[4 + i] += __builtin_amdgcn_exp2f(x1);
      }
    }
  }

  // extra S_v tile: x_row = dot(a_scaled, S_v) = sum of unmasked logits*C2
  f32x4 accx[2];
  {
    const ushort* Bx = r2x + (size_t)b * 16 * CC + (size_t)r * CC + kg * 8;
    bf16x8 bx0 = *reinterpret_cast<const bf16x8*>(Bx);
    bf16x8 bx1 = *reinterpret_cast<const bf16x8*>(Bx + 32);
    bf16x8 bx2 = *reinterpret_cast<const bf16x8*>(Bx + 64);
    bf16x8 bx3 = *reinterpret_cast<const bf16x8*>(Bx + 96);
#pragma unroll
    for (int g = 0; g < 2; g++) {
      f32x4 ax = {0.f, 0.f, 0.f, 0.f};
      ax = __builtin_amdgcn_mfma_f32_16x16x32_bf16(av[g][0], bx0, ax, 0, 0, 0);
      ax = __builtin_amdgcn_mfma_f32_16x16x32_bf16(av[g][1], bx1, ax, 0, 0, 0);
      ax = __builtin_amdgcn_mfma_f32_16x16x32_bf16(av[g][2], bx2, ax, 0, 0, 0);
      ax = __builtin_amdgcn_mfma_f32_16x16x32_bf16(av[g][3], bx3, ax, 0, 0, 0);
      accx[g] = ax;
    }
  }

  // reduce sAcc across the 16 r-lanes sharing each row
#pragma unroll
  for (int d = 1; d < 16; d <<= 1)
#pragma unroll
    for (int s = 0; s < 8; s++) sAcc[s] += __shfl_xor(sAcc[s], d);

  // x select: value for (row, col=rl) lives in lane kg*16 + rl, reg i
  float xsel[8];
#pragma unroll
  for (int g = 0; g < 2; g++)
#pragma unroll
    for (int i = 0; i < 4; i++)
      xsel[g * 4 + i] = __shfl(accx[g][i], (lane & 48) | rl[g * 4 + i]);

  float tv = 0.f;
  if (r == 0) {
#pragma unroll
    for (int g = 0; g < 2; g++)
#pragma unroll
      for (int i = 0; i < 4; i++) {
        int row = px0 + wrow0 + g * 16 + kg * 4 + i;
        float pv = posv[(size_t)b * NN + row];   // already * C2
        float s = sAcc[g * 4 + i] + __builtin_amdgcn_exp2f(pv);
        float x = xsel[g * 4 + i] + pv;
        tv += 1025.0f * __log2f(s) - x;
      }
  }
  tv += __shfl_xor(tv, 16);
  tv += __shfl_xor(tv, 32);
  if (lane == 0) atomicAdd(accum, tv);
}

// ---------------------------------------------------------------------------
__global__ void k_scale(const float* __restrict__ accum, float* __restrict__ out) {
  out[0] = accum[0] * SCALE;
}

// ---------------------------------------------------------------------------
extern "C" void kernel_launch(void* const* d_in, const int* in_sizes, int n_in,
                              void* d_out, int out_size, void* d_ws, size_t ws_size,
                              hipStream_t stream) {
  const float* z1 = (const float*)d_in[0];
  const float* z2 = (const float*)d_in[1];
  const int* lab = (const int*)d_in[2];

  char* ws = (char*)d_ws;
  uint* r2n   = (uint*)ws;                      // B*M*C bf16  = 524,288 B
  ushort* r2x = (ushort*)(ws + 524288);         // B*16*C bf16 =   8,192 B
  float* posv = (float*)(ws + 532480);          // B*N f32     = 524,288 B
  float* i1c2 = (float*)(ws + 1056768);         // B*N f32     = 524,288 B
  float* Sv   = (float*)(ws + 1581056);         // B*5*128 f32 =   5,120 B
  float* accum = (float*)(ws + 1586176);        //                     4 B

  hipMemsetAsync(ws + 1581056, 0, 5124, stream);  // Sv + accum

  k_pos<<<dim3(NN / 512, BB), 256, 0, stream>>>(z1, z2, i1c2, posv);
  k_r2<<<dim3(MM / 64, BB), 256, 0, stream>>>(z2, lab, r2n, Sv);
  k_svpack<<<dim3(16), 256, 0, stream>>>(Sv, r2x);
  k_gemm<<<dim3(NN / 128, BB), 256, 0, stream>>>(
      z1, i1c2, (const ushort*)r2n, r2x, lab, posv, accum);
  k_scale<<<1, 1, 0, stream>>>(accum, (float*)d_out);
}

// Round 5
// 284.753 us; speedup vs baseline: 1.1941x; 1.1941x over previous
//
#include <hip/hip_runtime.h>
#include <hip/hip_bf16.h>

constexpr int BB = 2;        // batch
constexpr int CC = 128;      // channels
constexpr int NN = 65536;    // H*W pixels
constexpr int MM = 1024;     // N / chunks
constexpr int LASTOFF = 63 * 1024;   // pixel offset of last chunk
constexpr float INV_T = 1.0f / 0.07f;
constexpr float L2E = 1.44269504088896340736f;  // log2(e)
constexpr float C2 = INV_T * L2E;               // fold /T and ln->log2 into A side
// loss = accum_base2 / (count * L2E); count = B*chunks*M*(M+1) = 134348800
constexpr float SCALE = 1.0f / (134348800.0f * 1.44269504088896340736f);
constexpr float EPSN = 1e-12f;

typedef float f32x4 __attribute__((ext_vector_type(4)));
typedef short bf16x8 __attribute__((ext_vector_type(8)));

__device__ __forceinline__ uint pack_bf16(float a, float b) {
  __hip_bfloat16 ha = __float2bfloat16(a);
  __hip_bfloat16 hb = __float2bfloat16(b);
  ushort ua = *reinterpret_cast<ushort*>(&ha);
  ushort ub = *reinterpret_cast<ushort*>(&hb);
  return (uint)ua | ((uint)ub << 16);
}

// ---------------------------------------------------------------------------
// K1: per-pixel norms + positive logit, channel-split for occupancy.
// Block = 128 px, 4 waves = 4 channel-groups of 32; LDS reduce across groups.
// Grid = 1024 blocks -> 4 blocks/CU, 16 waves/CU (vs 4 before).
__global__ __launch_bounds__(256) void k_pos(
    const float* __restrict__ z1, const float* __restrict__ z2,
    float* __restrict__ i1c2, float* __restrict__ posv) {
  __shared__ float part[3][4][132];
  const int b = blockIdx.y;
  const int px0 = blockIdx.x * 128;
  const int t = threadIdx.x;
  const int g = t >> 6;          // channel group 0..3 (32 ch each)
  const int pr = 2 * (t & 63);   // pixel pair within 128
  const float* p1 = z1 + (size_t)b * CC * NN + (size_t)(g * 32) * NN + px0 + pr;
  const float* p2 = z2 + (size_t)b * CC * NN + (size_t)(g * 32) * NN + px0 + pr;
  float s11a = 0.f, s22a = 0.f, s12a = 0.f;
  float s11b = 0.f, s22b = 0.f, s12b = 0.f;
#pragma unroll
  for (int e = 0; e < 32; e++) {
    float2 x = *reinterpret_cast<const float2*>(p1 + (size_t)e * NN);
    float2 y = *reinterpret_cast<const float2*>(p2 + (size_t)e * NN);
    s11a += x.x * x.x; s22a += y.x * y.x; s12a += x.x * y.x;
    s11b += x.y * x.y; s22b += y.y * y.y; s12b += x.y * y.y;
  }
  part[0][g][pr] = s11a; part[0][g][pr + 1] = s11b;
  part[1][g][pr] = s22a; part[1][g][pr + 1] = s22b;
  part[2][g][pr] = s12a; part[2][g][pr + 1] = s12b;
  __syncthreads();
  if (t < 128) {
    float s11 = part[0][0][t] + part[0][1][t] + part[0][2][t] + part[0][3][t];
    float s22 = part[1][0][t] + part[1][1][t] + part[1][2][t] + part[1][3][t];
    float s12 = part[2][0][t] + part[2][1][t] + part[2][2][t] + part[2][3][t];
    float i1 = 1.0f / fmaxf(sqrtf(s11), EPSN);
    float i2 = 1.0f / fmaxf(sqrtf(s22), EPSN);
    i1c2[(size_t)b * NN + px0 + t] = i1 * C2;
    posv[(size_t)b * NN + px0 + t] = s12 * i1 * i2 * C2;
  }
}

// ---------------------------------------------------------------------------
// K2: normalize + transpose + bf16 for z2's last chunk (B side, UNSCALED)
//     + per-label column-sum partials S_v = sum_{cl != v} col_n  (fp32 atomics).
__global__ __launch_bounds__(256) void k_r2(
    const float* __restrict__ z2, const int* __restrict__ lab,
    uint* __restrict__ r2n, float* __restrict__ Sv) {
  __shared__ float t2[64 * 129];
  __shared__ float part[8][65];
  __shared__ float inv2s[64];
  __shared__ int cls[64];
  const int b = blockIdx.y;
  const int pg = blockIdx.x * 64;          // within last chunk
  const int p0 = LASTOFF + pg;
  const int t = threadIdx.x;
  const int p2 = t & 31;
  const int q = t >> 5;
  const float* s2 = z2 + (size_t)b * CC * NN + p0 + 2 * p2;
  float a22 = 0.f, b22 = 0.f;
#pragma unroll
  for (int e = 0; e < 16; e++) {
    int c = e * 8 + q;
    float2 y = *reinterpret_cast<const float2*>(s2 + (size_t)c * NN);
    t2[(2 * p2) * 129 + c] = y.x;
    t2[(2 * p2 + 1) * 129 + c] = y.y;
    a22 += y.x * y.x;
    b22 += y.y * y.y;
  }
  part[q][2 * p2] = a22;
  part[q][2 * p2 + 1] = b22;
  __syncthreads();
  if (t < 64) {
    float s22 = 0.f;
#pragma unroll
    for (int qq = 0; qq < 8; qq++) s22 += part[qq][t];
    inv2s[t] = 1.0f / fmaxf(sqrtf(s22), EPSN);
    cls[t] = lab[(size_t)b * NN + p0 + t];
  }
  __syncthreads();
  const size_t obase = ((size_t)b * MM + pg) * 64;
#pragma unroll
  for (int e = 0; e < 16; e++) {
    int lin = e * 256 + t;
    int pp = lin >> 6;
    int cp = lin & 63;
    float i2 = inv2s[pp];
    float v0 = t2[pp * 129 + 2 * cp] * i2;
    float v1 = t2[pp * 129 + 2 * cp + 1] * i2;
    r2n[obase + (size_t)pp * 64 + cp] = pack_bf16(v0, v1);
  }
  // S_v partials: thread -> (channel c, pixel-half h)
  const int c = t & 127;
  const int h = t >> 7;
  float tot = 0.f, se0 = 0.f, se1 = 0.f, se2 = 0.f, se3 = 0.f, se4 = 0.f;
#pragma unroll
  for (int k = 0; k < 32; k++) {
    int pp = h * 32 + k;
    float val = t2[pp * 129 + c] * inv2s[pp];
    int lb = cls[pp];
    tot += val;
    se0 += (lb == 0) ? val : 0.f;
    se1 += (lb == 1) ? val : 0.f;
    se2 += (lb == 2) ? val : 0.f;
    se3 += (lb == 3) ? val : 0.f;
    se4 += (lb == 4) ? val : 0.f;
  }
  float* svb = Sv + b * 640 + c;
  atomicAdd(svb + 0 * 128, tot - se0);
  atomicAdd(svb + 1 * 128, tot - se1);
  atomicAdd(svb + 2 * 128, tot - se2);
  atomicAdd(svb + 3 * 128, tot - se3);
  atomicAdd(svb + 4 * 128, tot - se4);
}

// ---------------------------------------------------------------------------
// K3: pack S_v fp32 -> bf16 16-row extra B-tile (rows 5..15 zero).
__global__ void k_svpack(const float* __restrict__ Sv, ushort* __restrict__ r2x) {
  int i = blockIdx.x * 256 + threadIdx.x;  // 0..4095
  if (i >= BB * 16 * 128) return;
  int b = i >> 11, rr = (i >> 7) & 15, c = i & 127;
  float v = (rr < 5) ? Sv[b * 640 + rr * 128 + c] : 0.0f;
  __hip_bfloat16 h = __float2bfloat16(v);
  r2x[i] = *reinterpret_cast<ushort*>(&h);
}

// ---------------------------------------------------------------------------
// K4: GEMM + mask + exp2-sum partials. ONE wave per block, NO LDS, NO barriers.
// Wave = 64 rows x 512 cols (col-half split across blockIdx.y). A-fragments
// gathered per-lane from L3-hot z1 (scalar loads + bf16 pack, one-time),
// giving 4x B-reuse (16 B-loads feed 64 MFMA per 32-col chunk).
// Per-row partial sums stored to sp[half][row]; x-dot (S_v tile) to xp[row].
// C/D layout: col = lane&15, row = (lane>>4)*4 + reg.
__global__ __launch_bounds__(64) void k_gemm(
    const float* __restrict__ z1, const float* __restrict__ i1c2,
    const ushort* __restrict__ r2n, const ushort* __restrict__ r2x,
    const int* __restrict__ lab, float* __restrict__ sp,
    float* __restrict__ xp) {
  const int b = blockIdx.z;
  const int half = blockIdx.y;
  const int px0 = blockIdx.x * 64;
  const int lane = threadIdx.x;
  const int r = lane & 15;
  const int kg = lane >> 4;
  const size_t bN = (size_t)b * NN;

  // A fragments straight from global (z1 is L2/L3-hot after k_pos).
  bf16x8 av[4][4];
#pragma unroll
  for (int g = 0; g < 4; g++) {
    const int px = px0 + g * 16 + r;
    const float iv = i1c2[bN + px];
    const float* zc = z1 + bN * CC + px;
#pragma unroll
    for (int kk = 0; kk < 4; kk++) {
      const int c0 = kk * 32 + kg * 8;
      bf16x8 tv;
#pragma unroll
      for (int j = 0; j < 8; j++) {
        float v = zc[(size_t)(c0 + j) * NN] * iv;
        __hip_bfloat16 h = __float2bfloat16(v);
        tv[j] = *reinterpret_cast<short*>(&h);
      }
      av[g][kk] = tv;
    }
  }

  int rl[16];
#pragma unroll
  for (int g = 0; g < 4; g++)
#pragma unroll
    for (int i = 0; i < 4; i++)
      rl[g * 4 + i] = lab[bN + px0 + g * 16 + kg * 4 + i];

  float sAcc[16];
#pragma unroll
  for (int s = 0; s < 16; s++) sAcc[s] = 0.f;

  const ushort* Bh = r2n + ((size_t)b * MM + half * 512) * CC;
  const int* clbase = lab + bN + LASTOFF + half * 512;

#pragma unroll 2
  for (int nc = 0; nc < 16; nc++) {
    const int n0 = nc * 32;
    bf16x8 bv[2][4];
    int cl[2];
#pragma unroll
    for (int tt = 0; tt < 2; tt++) {
      const ushort* Bt = Bh + (size_t)(n0 + tt * 16 + r) * CC + kg * 8;
#pragma unroll
      for (int kk = 0; kk < 4; kk++)
        bv[tt][kk] = *reinterpret_cast<const bf16x8*>(Bt + kk * 32);
      cl[tt] = clbase[n0 + tt * 16 + r];
    }
    f32x4 acc[4][2];
#pragma unroll
    for (int g = 0; g < 4; g++)
#pragma unroll
      for (int tt = 0; tt < 2; tt++)
        acc[g][tt] = f32x4{0.f, 0.f, 0.f, 0.f};
#pragma unroll
    for (int kk = 0; kk < 4; kk++)
#pragma unroll
      for (int g = 0; g < 4; g++)
#pragma unroll
        for (int tt = 0; tt < 2; tt++)
          acc[g][tt] = __builtin_amdgcn_mfma_f32_16x16x32_bf16(
              av[g][kk], bv[tt][kk], acc[g][tt], 0, 0, 0);
    // acc = logit*C2 (A pre-scaled); masked -> exp2(0)=1 still in denominator.
#pragma unroll
    for (int g = 0; g < 4; g++)
#pragma unroll
      for (int tt = 0; tt < 2; tt++)
#pragma unroll
        for (int i = 0; i < 4; i++) {
          float x = (rl[g * 4 + i] != cl[tt]) ? acc[g][tt][i] : 0.0f;
          sAcc[g * 4 + i] += __builtin_amdgcn_exp2f(x);
        }
  }

  // reduce across the 16 col-lanes (r) sharing each row group
#pragma unroll
  for (int d = 1; d < 16; d <<= 1)
#pragma unroll
    for (int s = 0; s < 16; s++) sAcc[s] += __shfl_xor(sAcc[s], d);

  if (r == 0) {
#pragma unroll
    for (int s = 0; s < 16; s++) {
      int row = px0 + (s >> 2) * 16 + kg * 4 + (s & 3);
      sp[(size_t)half * (BB * (size_t)NN) + bN + row] = sAcc[s];
    }
  }

  if (half == 0) {
    // x_row = dot(a_scaled, S_rl) via the 16-col S_v tile
    bf16x8 bx[4];
    const ushort* Bx = r2x + (size_t)b * 16 * CC + (size_t)r * CC + kg * 8;
#pragma unroll
    for (int kk = 0; kk < 4; kk++)
      bx[kk] = *reinterpret_cast<const bf16x8*>(Bx + kk * 32);
    f32x4 accx[4];
#pragma unroll
    for (int g = 0; g < 4; g++) {
      f32x4 ax = {0.f, 0.f, 0.f, 0.f};
#pragma unroll
      for (int kk = 0; kk < 4; kk++)
        ax = __builtin_amdgcn_mfma_f32_16x16x32_bf16(av[g][kk], bx[kk], ax, 0, 0, 0);
      accx[g] = ax;
    }
    float xsel[16];
#pragma unroll
    for (int g = 0; g < 4; g++)
#pragma unroll
      for (int i = 0; i < 4; i++)
        xsel[g * 4 + i] = __shfl(accx[g][i], (lane & 48) | rl[g * 4 + i]);
    if (r == 0) {
#pragma unroll
      for (int s = 0; s < 16; s++) {
        int row = px0 + (s >> 2) * 16 + kg * 4 + (s & 3);
        xp[bN + row] = xsel[s];
      }
    }
  }
}

// ---------------------------------------------------------------------------
// K5: combine per-row partials -> loss sum (single atomic per block).
__global__ __launch_bounds__(256) void k_loss(
    const float* __restrict__ sp, const float* __restrict__ xp,
    const float* __restrict__ posv, float* __restrict__ accum) {
  __shared__ float red[4];
  const int idx = blockIdx.x * 256 + threadIdx.x;  // 0..BB*NN-1
  float pv = posv[idx];
  float s = sp[idx] + sp[BB * (size_t)NN + idx] + __builtin_amdgcn_exp2f(pv);
  float x = xp[idx] + pv;
  float tv = 1025.0f * __log2f(s) - x;
#pragma unroll
  for (int d = 1; d < 64; d <<= 1) tv += __shfl_xor(tv, d);
  if ((threadIdx.x & 63) == 0) red[threadIdx.x >> 6] = tv;
  __syncthreads();
  if (threadIdx.x == 0)
    atomicAdd(accum, red[0] + red[1] + red[2] + red[3]);
}

// ---------------------------------------------------------------------------
__global__ void k_scale(const float* __restrict__ accum, float* __restrict__ out) {
  out[0] = accum[0] * SCALE;
}

// ---------------------------------------------------------------------------
extern "C" void kernel_launch(void* const* d_in, const int* in_sizes, int n_in,
                              void* d_out, int out_size, void* d_ws, size_t ws_size,
                              hipStream_t stream) {
  const float* z1 = (const float*)d_in[0];
  const float* z2 = (const float*)d_in[1];
  const int* lab = (const int*)d_in[2];

  char* ws = (char*)d_ws;
  uint* r2n   = (uint*)ws;                      // B*M*C bf16   =   524,288 B
  ushort* r2x = (ushort*)(ws + 524288);         // B*16*C bf16  =     8,192 B
  float* posv = (float*)(ws + 532480);          // B*N f32      =   524,288 B
  float* i1c2 = (float*)(ws + 1056768);         // B*N f32      =   524,288 B
  float* Sv   = (float*)(ws + 1581056);         // B*5*128 f32  =     5,120 B
  float* accum = (float*)(ws + 1586176);        //                        4 B
  float* sp   = (float*)(ws + 1589248);         // 2*B*N f32    = 1,048,576 B
  float* xp   = (float*)(ws + 2637824);         // B*N f32      =   524,288 B

  hipMemsetAsync(ws + 1581056, 0, 5124, stream);  // Sv + accum

  k_pos<<<dim3(NN / 128, BB), 256, 0, stream>>>(z1, z2, i1c2, posv);
  k_r2<<<dim3(MM / 64, BB), 256, 0, stream>>>(z2, lab, r2n, Sv);
  k_svpack<<<dim3(16), 256, 0, stream>>>(Sv, r2x);
  k_gemm<<<dim3(NN / 64, 2, BB), 64, 0, stream>>>(
      z1, i1c2, (const ushort*)r2n, r2x, lab, sp, xp);
  k_loss<<<dim3(BB * NN / 256), 256, 0, stream>>>(sp, xp, posv, accum);
  k_scale<<<1, 1, 0, stream>>>(accum, (float*)d_out);
}